// Round 1
// baseline (524.173 us; speedup 1.0000x reference)
//
#include <hip/hip_runtime.h>

// ---------------------------------------------------------------------------
// GPT-Neo local self-attention, MI355X (gfx950).
// B=2, S=2048, D=2048, H=16, HD=128, WINDOW=256.
// Pipeline: split h -> transpose/split W -> QKV proj (split-bf16 3-pass GEMM)
//           -> flash window attention -> output GEMM (+bias).
// Precision: split-bf16 (hi*hi + hi*lo + lo*hi) for projections; plain bf16
// elsewhere; fp32 MFMA accumulation throughout.
// ---------------------------------------------------------------------------

#define S_LEN 2048
#define D_DIM 2048
#define NHEAD 16
#define HDIM  128
#define WIN   256

typedef __attribute__((ext_vector_type(8))) short bf16x8;
typedef __attribute__((ext_vector_type(4))) float f32x4;

__device__ __forceinline__ unsigned short f2bf(float f) {
  unsigned int u = __float_as_uint(f);
  unsigned int r = u + 0x7fffu + ((u >> 16) & 1u);   // round-to-nearest-even
  return (unsigned short)(r >> 16);
}
__device__ __forceinline__ float bf2f(unsigned short h) {
  return __uint_as_float(((unsigned int)h) << 16);
}

// async global->LDS, 16B per lane. LDS dest must be wave-uniform base + lane*16
// (we pass per-thread ptr = base + tid*16 which satisfies this per wave).
__device__ __forceinline__ void gload16(const void* g, void* l) {
  __builtin_amdgcn_global_load_lds(
      (const __attribute__((address_space(1))) unsigned int*)g,
      (__attribute__((address_space(3))) unsigned int*)l, 16, 0, 0);
}

// ---------------------------------------------------------------------------
// hidden (fp32) -> h_hi, h_lo (bf16).  8,388,608 elems, 4/thread.
__global__ __launch_bounds__(256) void k_split_h(
    const float* __restrict__ x, unsigned short* __restrict__ hi,
    unsigned short* __restrict__ lo) {
  int i = (blockIdx.x * 256 + threadIdx.x) * 4;
  float4 v = *(const float4*)(x + i);
  ushort4 a, b;
  a.x = f2bf(v.x); b.x = f2bf(v.x - bf2f(a.x));
  a.y = f2bf(v.y); b.y = f2bf(v.y - bf2f(a.y));
  a.z = f2bf(v.z); b.z = f2bf(v.z - bf2f(a.z));
  a.w = f2bf(v.w); b.w = f2bf(v.w - bf2f(a.w));
  *(ushort4*)(hi + i) = a;
  *(ushort4*)(lo + i) = b;
}

// ---------------------------------------------------------------------------
// W [k][n] fp32 -> Wt_hi/Wt_lo [n][k] bf16 (lo skipped for z==3 / Wo).
__global__ __launch_bounds__(256) void k_transw(
    const float* __restrict__ W0, const float* __restrict__ W1,
    const float* __restrict__ W2, const float* __restrict__ W3,
    unsigned short* __restrict__ wthi, unsigned short* __restrict__ wtlo) {
  __shared__ float tile[64][65];
  int z = blockIdx.z;
  const float* W = (z == 0) ? W0 : (z == 1) ? W1 : (z == 2) ? W2 : W3;
  int k0 = blockIdx.x * 64, n0 = blockIdx.y * 64;
  int c4 = (threadIdx.x & 15) * 4, rr = threadIdx.x >> 4;
#pragma unroll
  for (int p = 0; p < 4; ++p) {
    int row = rr + p * 16;
    float4 v = *(const float4*)(W + (size_t)(k0 + row) * D_DIM + n0 + c4);
    tile[row][c4 + 0] = v.x; tile[row][c4 + 1] = v.y;
    tile[row][c4 + 2] = v.z; tile[row][c4 + 3] = v.w;
  }
  __syncthreads();
  unsigned short* hp = wthi + (size_t)z * 4194304;
  unsigned short* lp = wtlo + (size_t)z * 4194304;
#pragma unroll
  for (int p = 0; p < 4; ++p) {
    int n = rr + p * 16;
    ushort4 hv, lv;
    float x0 = tile[c4 + 0][n], x1 = tile[c4 + 1][n];
    float x2 = tile[c4 + 2][n], x3 = tile[c4 + 3][n];
    hv.x = f2bf(x0); lv.x = f2bf(x0 - bf2f(hv.x));
    hv.y = f2bf(x1); lv.y = f2bf(x1 - bf2f(hv.y));
    hv.z = f2bf(x2); lv.z = f2bf(x2 - bf2f(hv.z));
    hv.w = f2bf(x3); lv.w = f2bf(x3 - bf2f(hv.w));
    size_t off = (size_t)(n0 + n) * D_DIM + k0 + c4;
    *(ushort4*)(hp + off) = hv;
    if (z < 3) *(ushort4*)(lp + off) = lv;
  }
}

// ---------------------------------------------------------------------------
// 128x128-tile GEMM, BK=64, 4 waves (2x2), 16x16x32 bf16 MFMA.
// A: [M][K] bf16 row-major (k-contig).  B: [N][K] bf16 (pre-transposed W).
// MODE 0: split 3-pass (hi*hi + hi*lo + lo*hi), grid.z in {0:q,1:k,2:v^T},
//         bf16 outputs.  MODE 1: plain 1-pass, fp32 out + bias.
// LDS tiles are written linearly by global_load_lds with the XOR swizzle
// pre-applied to the GLOBAL source column (rule #21); ds_reads apply the
// same swizzle (byte ^= (row&7)<<4) -> conflict-free ds_read_b128.
template <int MODE>
__global__ __launch_bounds__(256, 2) void k_gemm(
    const unsigned short* __restrict__ Ahi, const unsigned short* __restrict__ Alo,
    const unsigned short* __restrict__ Bhi, const unsigned short* __restrict__ Blo,
    unsigned short* __restrict__ oQ, unsigned short* __restrict__ oK,
    unsigned short* __restrict__ oVt, float* __restrict__ oF,
    const float* __restrict__ bias) {
  __shared__ __align__(16) unsigned short lA[128 * 64];
  __shared__ __align__(16) unsigned short lB[128 * 64];
  int tid = threadIdx.x;
  int m0 = blockIdx.y * 128, n0 = blockIdx.x * 128;
  int z = blockIdx.z;
  const unsigned short* bH = (MODE == 0) ? Bhi + (size_t)z * 4194304 : Bhi;
  const unsigned short* bL = (MODE == 0) ? Blo + (size_t)z * 4194304 : Bhi;

  f32x4 acc[4][4];
#pragma unroll
  for (int i = 0; i < 4; ++i)
#pragma unroll
    for (int j = 0; j < 4; ++j) acc[i][j] = (f32x4){0.f, 0.f, 0.f, 0.f};

  int w = tid >> 6, lane = tid & 63;
  int wm = (w >> 1) * 64, wn = (w & 1) * 64;
  int lr = lane & 15, lk = (lane >> 4) * 8;

  const int NSTEP = (MODE == 0) ? 96 : 32;
  for (int s = 0; s < NSTEP; ++s) {
    int p = s >> 5, kk = s & 31;
    const unsigned short* As = (MODE == 0 && p == 2) ? Alo : Ahi;
    const unsigned short* Bs = (MODE == 0 && p == 1) ? bL : bH;
    size_t aBase = (size_t)m0 * D_DIM + kk * 64;
    size_t bBase = (size_t)n0 * D_DIM + kk * 64;
#pragma unroll
    for (int it = 0; it < 4; ++it) {
      int slot = tid + it * 256;            // 1024 slots = 128 rows x 8 x16B
      int r = slot >> 3, c = slot & 7;
      int cs = c ^ (r & 7);                 // inverse swizzle on source
      gload16(As + aBase + (size_t)r * D_DIM + cs * 8, lA + slot * 8);
      gload16(Bs + bBase + (size_t)r * D_DIM + cs * 8, lB + slot * 8);
    }
    __syncthreads();
#pragma unroll
    for (int kc = 0; kc < 2; ++kc) {
      int kb = (kc * 32 + lk) * 2;
      bf16x8 af[4], bv[4];
#pragma unroll
      for (int mt = 0; mt < 4; ++mt) {
        int row = wm + mt * 16 + lr;
        int byte = (row * 128 + kb) ^ ((row & 7) << 4);
        af[mt] = *(const bf16x8*)((const char*)lA + byte);
      }
#pragma unroll
      for (int nt = 0; nt < 4; ++nt) {
        int row = wn + nt * 16 + lr;
        int byte = (row * 128 + kb) ^ ((row & 7) << 4);
        bv[nt] = *(const bf16x8*)((const char*)lB + byte);
      }
#pragma unroll
      for (int mt = 0; mt < 4; ++mt)
#pragma unroll
        for (int nt = 0; nt < 4; ++nt)
          acc[mt][nt] = __builtin_amdgcn_mfma_f32_16x16x32_bf16(
              af[mt], bv[nt], acc[mt][nt], 0, 0, 0);
    }
    __syncthreads();
  }

  // epilogue: C/D layout col=lane&15, row=(lane>>4)*4+reg (m89-verified)
  int lq = lane >> 4;
#pragma unroll
  for (int mt = 0; mt < 4; ++mt) {
#pragma unroll
    for (int nt = 0; nt < 4; ++nt) {
      int col = n0 + wn + nt * 16 + lr;
      int row0 = m0 + wm + mt * 16 + lq * 4;
      if (MODE == 1) {
        float bvs = bias[col];
#pragma unroll
        for (int r = 0; r < 4; ++r)
          oF[(size_t)(row0 + r) * D_DIM + col] = acc[mt][nt][r] + bvs;
      } else if (z < 2) {
        unsigned short* dst = (z == 0) ? oQ : oK;
        size_t base = (((size_t)(row0 >> 11) * NHEAD + (col >> 7)) * S_LEN) * HDIM;
#pragma unroll
        for (int r = 0; r < 4; ++r)
          dst[base + (size_t)((row0 + r) & 2047) * HDIM + (col & 127)] =
              f2bf(acc[mt][nt][r]);
      } else {  // v, written transposed: vt[b][h][hd][s]
        ushort4 pk;
        pk.x = f2bf(acc[mt][nt][0]); pk.y = f2bf(acc[mt][nt][1]);
        pk.z = f2bf(acc[mt][nt][2]); pk.w = f2bf(acc[mt][nt][3]);
        size_t base = (((size_t)(row0 >> 11) * NHEAD + (col >> 7)) * HDIM +
                       (col & 127)) * S_LEN;
        *(ushort4*)(oVt + base + (row0 & 2047)) = pk;
      }
    }
  }
}

// ---------------------------------------------------------------------------
// Flash-style sliding-window attention. Block = (b, h, 64-query tile),
// 4 waves x 16 query rows. KV tiles of 64. q,k: [b][h][s][hd]; v: [b][h][hd][s].
__global__ __launch_bounds__(256, 2) void k_attn(
    const unsigned short* __restrict__ q, const unsigned short* __restrict__ kx,
    const unsigned short* __restrict__ vt, const int* __restrict__ amask,
    unsigned short* __restrict__ attn) {
  __shared__ __align__(16) unsigned short Qs[64 * 128];
  __shared__ __align__(16) unsigned short Ks[64 * 128];
  __shared__ __align__(16) unsigned short Vs[128 * 64];
  __shared__ __align__(16) unsigned short Ps[4][16 * 64];
  int tid = threadIdx.x;
  int b = blockIdx.z, h = blockIdx.y, q0 = blockIdx.x * 64;
  const size_t headOff = ((size_t)b * NHEAD + h) * S_LEN * HDIM;
  const unsigned short* qb = q + headOff;
  const unsigned short* kb = kx + headOff;
  const unsigned short* vb = vt + headOff;  // [128][2048]

  // stage Q once (rows 256B = 16 slots; source pre-swizzled)
#pragma unroll
  for (int it = 0; it < 4; ++it) {
    int slot = tid + it * 256;
    int r = slot >> 4, c = slot & 15, cs = c ^ (r & 7);
    gload16(qb + (size_t)(q0 + r) * HDIM + cs * 8, Qs + slot * 8);
  }

  int w = tid >> 6, lane = tid & 63;
  int lr = lane & 15, lq = lane >> 4, lk = lq * 8;
  const float NEGINF = -__builtin_inff();

  float m_pr[4], l_pr[4];
  f32x4 accO[8];
#pragma unroll
  for (int r = 0; r < 4; ++r) { m_pr[r] = NEGINF; l_pr[r] = 0.f; }
#pragma unroll
  for (int d = 0; d < 8; ++d) accO[d] = (f32x4){0.f, 0.f, 0.f, 0.f};

  int lo = q0 - (WIN - 1); if (lo < 0) lo = 0;
  int t0 = lo >> 6, t1 = q0 >> 6;
  for (int kt = t0; kt <= t1; ++kt) {
    int kv0 = kt * 64;
    __syncthreads();  // previous iteration's LDS reads complete
#pragma unroll
    for (int it = 0; it < 4; ++it) {
      int slot = tid + it * 256;
      int r = slot >> 4, c = slot & 15, cs = c ^ (r & 7);
      gload16(kb + (size_t)(kv0 + r) * HDIM + cs * 8, Ks + slot * 8);
    }
#pragma unroll
    for (int it = 0; it < 4; ++it) {
      int slot = tid + it * 256;
      int r = slot >> 3, c = slot & 7, cs = c ^ (r & 7);
      gload16(vb + (size_t)r * S_LEN + kv0 + cs * 8, Vs + slot * 8);
    }
    __syncthreads();

    // S = Q K^T  (reduce over d=128 in 4 chunks of 32)
    bf16x8 af[4];
#pragma unroll
    for (int kc = 0; kc < 4; ++kc) {
      int row = w * 16 + lr;
      int byte = (row * 256 + (kc * 32 + lk) * 2) ^ ((row & 7) << 4);
      af[kc] = *(const bf16x8*)((const char*)Qs + byte);
    }
    f32x4 sc[4];
#pragma unroll
    for (int jt = 0; jt < 4; ++jt) {
      sc[jt] = (f32x4){0.f, 0.f, 0.f, 0.f};
#pragma unroll
      for (int kc = 0; kc < 4; ++kc) {
        int row = jt * 16 + lr;
        int byte = (row * 256 + (kc * 32 + lk) * 2) ^ ((row & 7) << 4);
        bf16x8 bv = *(const bf16x8*)((const char*)Ks + byte);
        sc[jt] = __builtin_amdgcn_mfma_f32_16x16x32_bf16(af[kc], bv, sc[jt], 0, 0, 0);
      }
    }

    // band + attention_mask, online softmax (rows live on 16-lane groups)
    int iBase = q0 + w * 16 + lq * 4;
    float mt_[4] = {NEGINF, NEGINF, NEGINF, NEGINF};
#pragma unroll
    for (int jt = 0; jt < 4; ++jt) {
      int jg = kv0 + jt * 16 + lr;
      int mk = amask[b * S_LEN + jg];
#pragma unroll
      for (int r = 0; r < 4; ++r) {
        int ig = iBase + r;
        bool valid = (jg <= ig) && (ig - jg < WIN) && (mk != 0);
        float sv = valid ? sc[jt][r] : NEGINF;
        sc[jt][r] = sv;
        mt_[r] = fmaxf(mt_[r], sv);
      }
    }
#pragma unroll
    for (int off = 1; off < 16; off <<= 1)
#pragma unroll
      for (int r = 0; r < 4; ++r) mt_[r] = fmaxf(mt_[r], __shfl_xor(mt_[r], off));

    float scale[4], psum[4];
#pragma unroll
    for (int r = 0; r < 4; ++r) {
      float mn = fmaxf(m_pr[r], mt_[r]);
      scale[r] = (m_pr[r] == NEGINF) ? 0.f : __expf(m_pr[r] - mn);
      m_pr[r] = mn;
      psum[r] = 0.f;
    }
#pragma unroll
    for (int jt = 0; jt < 4; ++jt) {
#pragma unroll
      for (int r = 0; r < 4; ++r) {
        float sv = sc[jt][r];
        float p = (sv == NEGINF) ? 0.f : __expf(sv - m_pr[r]);
        psum[r] += p;
        int prow = lq * 4 + r;
        int byte = (prow * 128 + (jt * 16 + lr) * 2) ^ ((prow & 7) << 4);
        *(unsigned short*)((char*)Ps[w] + byte) = f2bf(p);
      }
    }
#pragma unroll
    for (int off = 1; off < 16; off <<= 1)
#pragma unroll
      for (int r = 0; r < 4; ++r) psum[r] += __shfl_xor(psum[r], off);
#pragma unroll
    for (int r = 0; r < 4; ++r) l_pr[r] = l_pr[r] * scale[r] + psum[r];
#pragma unroll
    for (int d = 0; d < 8; ++d)
#pragma unroll
      for (int r = 0; r < 4; ++r) accO[d][r] *= scale[r];
    __syncthreads();  // P visible to all lanes of the wave's group

    // O += P V   (reduce over j=64 in 2 chunks of 32)
    bf16x8 pa[2];
#pragma unroll
    for (int kc = 0; kc < 2; ++kc) {
      int byte = (lr * 128 + (kc * 32 + lk) * 2) ^ ((lr & 7) << 4);
      pa[kc] = *(const bf16x8*)((const char*)Ps[w] + byte);
    }
#pragma unroll
    for (int dt = 0; dt < 8; ++dt) {
#pragma unroll
      for (int kc = 0; kc < 2; ++kc) {
        int row = dt * 16 + lr;
        int byte = (row * 128 + (kc * 32 + lk) * 2) ^ ((row & 7) << 4);
        bf16x8 bv = *(const bf16x8*)((const char*)Vs + byte);
        accO[dt] = __builtin_amdgcn_mfma_f32_16x16x32_bf16(pa[kc], bv, accO[dt], 0, 0, 0);
      }
    }
  }

  // normalize + write attn[b][s][h*128+d] (bf16)
#pragma unroll
  for (int dt = 0; dt < 8; ++dt) {
#pragma unroll
    for (int r = 0; r < 4; ++r) {
      int row = q0 + w * 16 + lq * 4 + r;
      int col = h * HDIM + dt * 16 + lr;
      float v = accO[dt][r] / l_pr[r];
      attn[((size_t)b * S_LEN + row) * D_DIM + col] = f2bf(v);
    }
  }
}

// ---------------------------------------------------------------------------
extern "C" void kernel_launch(void* const* d_in, const int* in_sizes, int n_in,
                              void* d_out, int out_size, void* d_ws, size_t ws_size,
                              hipStream_t stream) {
  const float* hid = (const float*)d_in[0];
  const int* amask = (const int*)d_in[1];
  const float* Wq = (const float*)d_in[2];
  const float* Wk = (const float*)d_in[3];
  const float* Wv = (const float*)d_in[4];
  const float* Wo = (const float*)d_in[5];
  const float* bo = (const float*)d_in[6];
  float* out = (float*)d_out;

  // workspace layout (bytes); total 159,383,552
  char* ws = (char*)d_ws;
  unsigned short* hhi  = (unsigned short*)(ws);                 // 16 MB
  unsigned short* hlo  = (unsigned short*)(ws + 16777216);      // 16 MB
  unsigned short* wthi = (unsigned short*)(ws + 33554432);      // 4 x 8 MB
  unsigned short* wtlo = (unsigned short*)(ws + 67108864);      // 3 x 8 MB
  unsigned short* qB   = (unsigned short*)(ws + 92274688);      // 16 MB
  unsigned short* kB   = (unsigned short*)(ws + 109051904);     // 16 MB
  unsigned short* vtB  = (unsigned short*)(ws + 125829120);     // 16 MB
  unsigned short* attn = (unsigned short*)(ws + 142606336);     // 16 MB

  k_split_h<<<8192, 256, 0, stream>>>(hid, hhi, hlo);
  k_transw<<<dim3(32, 32, 4), 256, 0, stream>>>(Wq, Wk, Wv, Wo, wthi, wtlo);
  k_gemm<0><<<dim3(16, 32, 3), 256, 0, stream>>>(hhi, hlo, wthi, wtlo,
                                                 qB, kB, vtB, nullptr, nullptr);
  k_attn<<<dim3(32, 16, 2), 256, 0, stream>>>(qB, kB, vtB, amask, attn);
  k_gemm<1><<<dim3(16, 32, 1), 256, 0, stream>>>(attn, attn,
                                                 wthi + (size_t)3 * 4194304, nullptr,
                                                 nullptr, nullptr, nullptr, out, bo);
}

// Round 2
// 338.049 us; speedup vs baseline: 1.5506x; 1.5506x over previous
//
#include <hip/hip_runtime.h>

// ---------------------------------------------------------------------------
// GPT-Neo local self-attention, MI355X (gfx950).
// B=2, S=2048, D=2048, H=16, HD=128, WINDOW=256.
// Pipeline: cvt h->fp16 -> transpose/cvt W->fp16 -> QKV proj (fp16 GEMM)
//           -> flash window attention (fp16) -> output GEMM (+bias).
// Precision: fp16 operands everywhere, fp32 MFMA accumulation. fp16 rounding
// (2^-11/operand) keeps absmax ~8x below the bf16 variant's 0.046.
// ---------------------------------------------------------------------------

#define S_LEN 2048
#define D_DIM 2048
#define NHEAD 16
#define HDIM  128
#define WIN   256

typedef __attribute__((ext_vector_type(8))) _Float16 f16x8;
typedef __attribute__((ext_vector_type(4))) float f32x4;

__device__ __forceinline__ unsigned short f2h(float f) {
  _Float16 h = (_Float16)f;   // v_cvt_f16_f32, RTNE
  unsigned short u;
  __builtin_memcpy(&u, &h, 2);
  return u;
}

// async global->LDS, 16B per lane (wave-uniform base + lane*16).
__device__ __forceinline__ void gload16(const void* g, void* l) {
  __builtin_amdgcn_global_load_lds(
      (const __attribute__((address_space(1))) unsigned int*)g,
      (__attribute__((address_space(3))) unsigned int*)l, 16, 0, 0);
}

// ---------------------------------------------------------------------------
// hidden (fp32) -> fp16.  8,388,608 elems, 4/thread.
__global__ __launch_bounds__(256) void k_cvt_h(
    const float* __restrict__ x, unsigned short* __restrict__ h16) {
  int i = (blockIdx.x * 256 + threadIdx.x) * 4;
  float4 v = *(const float4*)(x + i);
  ushort4 a;
  a.x = f2h(v.x); a.y = f2h(v.y); a.z = f2h(v.z); a.w = f2h(v.w);
  *(ushort4*)(h16 + i) = a;
}

// ---------------------------------------------------------------------------
// W [k][n] fp32 -> Wt [n][k] fp16, all four weight matrices.
__global__ __launch_bounds__(256) void k_transw(
    const float* __restrict__ W0, const float* __restrict__ W1,
    const float* __restrict__ W2, const float* __restrict__ W3,
    unsigned short* __restrict__ wt) {
  __shared__ float tile[64][65];
  int z = blockIdx.z;
  const float* W = (z == 0) ? W0 : (z == 1) ? W1 : (z == 2) ? W2 : W3;
  int k0 = blockIdx.x * 64, n0 = blockIdx.y * 64;
  int c4 = (threadIdx.x & 15) * 4, rr = threadIdx.x >> 4;
#pragma unroll
  for (int p = 0; p < 4; ++p) {
    int row = rr + p * 16;
    float4 v = *(const float4*)(W + (size_t)(k0 + row) * D_DIM + n0 + c4);
    tile[row][c4 + 0] = v.x; tile[row][c4 + 1] = v.y;
    tile[row][c4 + 2] = v.z; tile[row][c4 + 3] = v.w;
  }
  __syncthreads();
  unsigned short* hp = wt + (size_t)z * 4194304;
#pragma unroll
  for (int p = 0; p < 4; ++p) {
    int n = rr + p * 16;
    ushort4 hv;
    hv.x = f2h(tile[c4 + 0][n]); hv.y = f2h(tile[c4 + 1][n]);
    hv.z = f2h(tile[c4 + 2][n]); hv.w = f2h(tile[c4 + 3][n]);
    *(ushort4*)(hp + (size_t)(n0 + n) * D_DIM + k0 + c4) = hv;
  }
}

// ---------------------------------------------------------------------------
// 128x128-tile GEMM, BK=64, 4 waves (2x2), 16x16x32 fp16 MFMA.
// A: [M][K] fp16 row-major (k-contig).  B: [N][K] fp16 (pre-transposed W).
// MODE 0: grid.z in {0:q,1:k,2:v^T}, fp16 outputs.  MODE 1: fp32 out + bias.
// LDS written linearly by global_load_lds with the XOR swizzle pre-applied to
// the GLOBAL source column (rule #21); ds_reads apply the same swizzle
// (byte ^= (row&7)<<4) -> conflict-free ds_read_b128.
template <int MODE>
__global__ __launch_bounds__(256, 2) void k_gemm(
    const unsigned short* __restrict__ A, const unsigned short* __restrict__ Bmat,
    unsigned short* __restrict__ oQ, unsigned short* __restrict__ oK,
    unsigned short* __restrict__ oVt, float* __restrict__ oF,
    const float* __restrict__ bias) {
  __shared__ __align__(16) unsigned short lA[128 * 64];
  __shared__ __align__(16) unsigned short lB[128 * 64];
  int tid = threadIdx.x;
  int m0 = blockIdx.y * 128, n0 = blockIdx.x * 128;
  int z = blockIdx.z;
  const unsigned short* Bz = (MODE == 0) ? Bmat + (size_t)z * 4194304 : Bmat;

  f32x4 acc[4][4];
#pragma unroll
  for (int i = 0; i < 4; ++i)
#pragma unroll
    for (int j = 0; j < 4; ++j) acc[i][j] = (f32x4){0.f, 0.f, 0.f, 0.f};

  int w = tid >> 6, lane = tid & 63;
  int wm = (w >> 1) * 64, wn = (w & 1) * 64;
  int lr = lane & 15, lk = (lane >> 4) * 8;

  for (int s = 0; s < 32; ++s) {
    size_t aBase = (size_t)m0 * D_DIM + s * 64;
    size_t bBase = (size_t)n0 * D_DIM + s * 64;
#pragma unroll
    for (int it = 0; it < 4; ++it) {
      int slot = tid + it * 256;            // 1024 slots = 128 rows x 8 x16B
      int r = slot >> 3, c = slot & 7;
      int cs = c ^ (r & 7);                 // inverse swizzle on source
      gload16(A + aBase + (size_t)r * D_DIM + cs * 8, lA + slot * 8);
      gload16(Bz + bBase + (size_t)r * D_DIM + cs * 8, lB + slot * 8);
    }
    __syncthreads();
#pragma unroll
    for (int kc = 0; kc < 2; ++kc) {
      int kb = (kc * 32 + lk) * 2;
      f16x8 af[4], bv[4];
#pragma unroll
      for (int mt = 0; mt < 4; ++mt) {
        int row = wm + mt * 16 + lr;
        int byte = (row * 128 + kb) ^ ((row & 7) << 4);
        af[mt] = *(const f16x8*)((const char*)lA + byte);
      }
#pragma unroll
      for (int nt = 0; nt < 4; ++nt) {
        int row = wn + nt * 16 + lr;
        int byte = (row * 128 + kb) ^ ((row & 7) << 4);
        bv[nt] = *(const f16x8*)((const char*)lB + byte);
      }
#pragma unroll
      for (int mt = 0; mt < 4; ++mt)
#pragma unroll
        for (int nt = 0; nt < 4; ++nt)
          acc[mt][nt] = __builtin_amdgcn_mfma_f32_16x16x32_f16(
              af[mt], bv[nt], acc[mt][nt], 0, 0, 0);
    }
    __syncthreads();
  }

  // epilogue: C/D layout col=lane&15, row=(lane>>4)*4+reg (m89-verified)
  int lq = lane >> 4;
#pragma unroll
  for (int mt = 0; mt < 4; ++mt) {
#pragma unroll
    for (int nt = 0; nt < 4; ++nt) {
      int col = n0 + wn + nt * 16 + lr;
      int row0 = m0 + wm + mt * 16 + lq * 4;
      if (MODE == 1) {
        float bvs = bias[col];
#pragma unroll
        for (int r = 0; r < 4; ++r)
          oF[(size_t)(row0 + r) * D_DIM + col] = acc[mt][nt][r] + bvs;
      } else if (z < 2) {
        unsigned short* dst = (z == 0) ? oQ : oK;
        size_t base = (((size_t)(row0 >> 11) * NHEAD + (col >> 7)) * S_LEN) * HDIM;
#pragma unroll
        for (int r = 0; r < 4; ++r)
          dst[base + (size_t)((row0 + r) & 2047) * HDIM + (col & 127)] =
              f2h(acc[mt][nt][r]);
      } else {  // v, written transposed: vt[b][h][hd][s]
        ushort4 pk;
        pk.x = f2h(acc[mt][nt][0]); pk.y = f2h(acc[mt][nt][1]);
        pk.z = f2h(acc[mt][nt][2]); pk.w = f2h(acc[mt][nt][3]);
        size_t base = (((size_t)(row0 >> 11) * NHEAD + (col >> 7)) * HDIM +
                       (col & 127)) * S_LEN;
        *(ushort4*)(oVt + base + (row0 & 2047)) = pk;
      }
    }
  }
}

// ---------------------------------------------------------------------------
// Flash-style sliding-window attention. Block = (b, h, 64-query tile),
// 4 waves x 16 query rows. KV tiles of 64. q,k: [b][h][s][hd]; v: [b][h][hd][s].
__global__ __launch_bounds__(256, 2) void k_attn(
    const unsigned short* __restrict__ q, const unsigned short* __restrict__ kx,
    const unsigned short* __restrict__ vt, const int* __restrict__ amask,
    unsigned short* __restrict__ attn) {
  __shared__ __align__(16) unsigned short Qs[64 * 128];
  __shared__ __align__(16) unsigned short Ks[64 * 128];
  __shared__ __align__(16) unsigned short Vs[128 * 64];
  __shared__ __align__(16) unsigned short Ps[4][16 * 64];
  int tid = threadIdx.x;
  int b = blockIdx.z, h = blockIdx.y, q0 = blockIdx.x * 64;
  const size_t headOff = ((size_t)b * NHEAD + h) * S_LEN * HDIM;
  const unsigned short* qb = q + headOff;
  const unsigned short* kb = kx + headOff;
  const unsigned short* vb = vt + headOff;  // [128][2048]

  // stage Q once (rows 256B = 16 slots; source pre-swizzled)
#pragma unroll
  for (int it = 0; it < 4; ++it) {
    int slot = tid + it * 256;
    int r = slot >> 4, c = slot & 15, cs = c ^ (r & 7);
    gload16(qb + (size_t)(q0 + r) * HDIM + cs * 8, Qs + slot * 8);
  }

  int w = tid >> 6, lane = tid & 63;
  int lr = lane & 15, lq = lane >> 4, lk = lq * 8;
  const float NEGINF = -__builtin_inff();

  float m_pr[4], l_pr[4];
  f32x4 accO[8];
#pragma unroll
  for (int r = 0; r < 4; ++r) { m_pr[r] = NEGINF; l_pr[r] = 0.f; }
#pragma unroll
  for (int d = 0; d < 8; ++d) accO[d] = (f32x4){0.f, 0.f, 0.f, 0.f};

  int lo = q0 - (WIN - 1); if (lo < 0) lo = 0;
  int t0 = lo >> 6, t1 = q0 >> 6;
  for (int kt = t0; kt <= t1; ++kt) {
    int kv0 = kt * 64;
    __syncthreads();  // previous iteration's LDS reads complete
#pragma unroll
    for (int it = 0; it < 4; ++it) {
      int slot = tid + it * 256;
      int r = slot >> 4, c = slot & 15, cs = c ^ (r & 7);
      gload16(kb + (size_t)(kv0 + r) * HDIM + cs * 8, Ks + slot * 8);
    }
#pragma unroll
    for (int it = 0; it < 4; ++it) {
      int slot = tid + it * 256;
      int r = slot >> 3, c = slot & 7, cs = c ^ (r & 7);
      gload16(vb + (size_t)r * S_LEN + kv0 + cs * 8, Vs + slot * 8);
    }
    __syncthreads();

    // S = Q K^T  (reduce over d=128 in 4 chunks of 32)
    f16x8 af[4];
#pragma unroll
    for (int kc = 0; kc < 4; ++kc) {
      int row = w * 16 + lr;
      int byte = (row * 256 + (kc * 32 + lk) * 2) ^ ((row & 7) << 4);
      af[kc] = *(const f16x8*)((const char*)Qs + byte);
    }
    f32x4 sc[4];
#pragma unroll
    for (int jt = 0; jt < 4; ++jt) {
      sc[jt] = (f32x4){0.f, 0.f, 0.f, 0.f};
#pragma unroll
      for (int kc = 0; kc < 4; ++kc) {
        int row = jt * 16 + lr;
        int byte = (row * 256 + (kc * 32 + lk) * 2) ^ ((row & 7) << 4);
        f16x8 bv = *(const f16x8*)((const char*)Ks + byte);
        sc[jt] = __builtin_amdgcn_mfma_f32_16x16x32_f16(af[kc], bv, sc[jt], 0, 0, 0);
      }
    }

    // band + attention_mask, online softmax (rows live on 16-lane groups)
    int iBase = q0 + w * 16 + lq * 4;
    float mt_[4] = {NEGINF, NEGINF, NEGINF, NEGINF};
#pragma unroll
    for (int jt = 0; jt < 4; ++jt) {
      int jg = kv0 + jt * 16 + lr;
      int mk = amask[b * S_LEN + jg];
#pragma unroll
      for (int r = 0; r < 4; ++r) {
        int ig = iBase + r;
        bool valid = (jg <= ig) && (ig - jg < WIN) && (mk != 0);
        float sv = valid ? sc[jt][r] : NEGINF;
        sc[jt][r] = sv;
        mt_[r] = fmaxf(mt_[r], sv);
      }
    }
#pragma unroll
    for (int off = 1; off < 16; off <<= 1)
#pragma unroll
      for (int r = 0; r < 4; ++r) mt_[r] = fmaxf(mt_[r], __shfl_xor(mt_[r], off));

    float scale[4], psum[4];
#pragma unroll
    for (int r = 0; r < 4; ++r) {
      float mn = fmaxf(m_pr[r], mt_[r]);
      scale[r] = (m_pr[r] == NEGINF) ? 0.f : __expf(m_pr[r] - mn);
      m_pr[r] = mn;
      psum[r] = 0.f;
    }
#pragma unroll
    for (int jt = 0; jt < 4; ++jt) {
#pragma unroll
      for (int r = 0; r < 4; ++r) {
        float sv = sc[jt][r];
        float p = (sv == NEGINF) ? 0.f : __expf(sv - m_pr[r]);
        psum[r] += p;
        int prow = lq * 4 + r;
        int byte = (prow * 128 + (jt * 16 + lr) * 2) ^ ((prow & 7) << 4);
        *(unsigned short*)((char*)Ps[w] + byte) = f2h(p);
      }
    }
#pragma unroll
    for (int off = 1; off < 16; off <<= 1)
#pragma unroll
      for (int r = 0; r < 4; ++r) psum[r] += __shfl_xor(psum[r], off);
#pragma unroll
    for (int r = 0; r < 4; ++r) l_pr[r] = l_pr[r] * scale[r] + psum[r];
#pragma unroll
    for (int d = 0; d < 8; ++d)
#pragma unroll
      for (int r = 0; r < 4; ++r) accO[d][r] *= scale[r];
    __syncthreads();  // P visible to all lanes of the wave's group

    // O += P V   (reduce over j=64 in 2 chunks of 32)
    f16x8 pa[2];
#pragma unroll
    for (int kc = 0; kc < 2; ++kc) {
      int byte = (lr * 128 + (kc * 32 + lk) * 2) ^ ((lr & 7) << 4);
      pa[kc] = *(const f16x8*)((const char*)Ps[w] + byte);
    }
#pragma unroll
    for (int dt = 0; dt < 8; ++dt) {
#pragma unroll
      for (int kc = 0; kc < 2; ++kc) {
        int row = dt * 16 + lr;
        int byte = (row * 128 + (kc * 32 + lk) * 2) ^ ((row & 7) << 4);
        f16x8 bv = *(const f16x8*)((const char*)Vs + byte);
        accO[dt] = __builtin_amdgcn_mfma_f32_16x16x32_f16(pa[kc], bv, accO[dt], 0, 0, 0);
      }
    }
  }

  // normalize + write attn[b][s][h*128+d] (fp16)
#pragma unroll
  for (int dt = 0; dt < 8; ++dt) {
#pragma unroll
    for (int r = 0; r < 4; ++r) {
      int row = q0 + w * 16 + lq * 4 + r;
      int col = h * HDIM + dt * 16 + lr;
      float v = accO[dt][r] / l_pr[r];
      attn[((size_t)b * S_LEN + row) * D_DIM + col] = f2h(v);
    }
  }
}

// ---------------------------------------------------------------------------
extern "C" void kernel_launch(void* const* d_in, const int* in_sizes, int n_in,
                              void* d_out, int out_size, void* d_ws, size_t ws_size,
                              hipStream_t stream) {
  const float* hid = (const float*)d_in[0];
  const int* amask = (const int*)d_in[1];
  const float* Wq = (const float*)d_in[2];
  const float* Wk = (const float*)d_in[3];
  const float* Wv = (const float*)d_in[4];
  const float* Wo = (const float*)d_in[5];
  const float* bo = (const float*)d_in[6];
  float* out = (float*)d_out;

  // workspace layout (bytes); total 117,440,512
  char* ws = (char*)d_ws;
  unsigned short* h16  = (unsigned short*)(ws);                 // 16 MB
  unsigned short* wt   = (unsigned short*)(ws + 16777216);      // 4 x 8 MB
  unsigned short* qB   = (unsigned short*)(ws + 50331648);      // 16 MB
  unsigned short* kB   = (unsigned short*)(ws + 67108864);      // 16 MB
  unsigned short* vtB  = (unsigned short*)(ws + 83886080);      // 16 MB
  unsigned short* attn = (unsigned short*)(ws + 100663296);     // 16 MB

  k_cvt_h<<<8192, 256, 0, stream>>>(hid, h16);
  k_transw<<<dim3(32, 32, 4), 256, 0, stream>>>(Wq, Wk, Wv, Wo, wt);
  k_gemm<0><<<dim3(16, 32, 3), 256, 0, stream>>>(h16, wt, qB, kB, vtB,
                                                 nullptr, nullptr);
  k_attn<<<dim3(32, 16, 2), 256, 0, stream>>>(qB, kB, vtB, amask, attn);
  k_gemm<1><<<dim3(16, 32, 1), 256, 0, stream>>>(attn, wt + (size_t)3 * 4194304,
                                                 nullptr, nullptr, nullptr, out, bo);
}